// Round 3
// baseline (214.650 us; speedup 1.0000x reference)
//
#include <hip/hip_runtime.h>
#include <cstddef>

// SNN collapse: alpha = expf(-1/0.005) = expf(-200) == 0.0f in fp32, so
// LIF(spiking) == floor(relu(x)) elementwise and LIF(readout) == identity.
// (Verified R1/R2: absmax 0.0.) Per-image feed-forward CNN, fully fused,
// one block per image, intermediates in LDS.
//
// R3: t1 stored as bf16 in LDS. t1 values are floor(relu(.)) = small
// non-negative integers (< 256), which are EXACT in bf16 (low 16 fp32 bits
// are zero), so truncation preserves bit-exact fp32 compute.
// LDS 47.4 KB -> 28.9 KB: 3 -> 5 blocks/CU.

__device__ __forceinline__ float bf_lo(unsigned int u) {
    union { unsigned int i; float f; } c; c.i = u << 16; return c.f;
}
__device__ __forceinline__ float bf_hi(unsigned int u) {
    union { unsigned int i; float f; } c; c.i = u & 0xffff0000u; return c.f;
}
__device__ __forceinline__ unsigned short f2bf(float f) {
    union { float f; unsigned int i; } c; c.f = f; return (unsigned short)(c.i >> 16);
}

__global__ __launch_bounds__(256, 5) void fused_snn(
    const float* __restrict__ x,    // (1024,2,128,128)
    const float* __restrict__ w1,   // (8,2,2,2)
    const float* __restrict__ w2,   // (8,8,3,3)
    const float* __restrict__ w3,   // (8,8,3,3)
    const float* __restrict__ wfc,  // (2,512)
    float* __restrict__ out)        // (1024,2)
{
    __shared__ unsigned short t1[8][34][34];        // conv1 pooled out, bf16, zero-padded: 18.5 KB
    __shared__ __align__(16) float t2[8][18][18];   // conv2 pooled out, fp32, zero-padded: 10.4 KB
    __shared__ float red[8];

    const int n = blockIdx.x;
    const int t = threadIdx.x;

    // zero-init LDS (borders must be zero)
    {
        unsigned int* z1 = (unsigned int*)&t1[0][0][0];   // 9248 ushorts = 4624 uints
        for (int i = t; i < 4624; i += 256) z1[i] = 0u;
        for (int i = t; i < 8 * 18 * 18; i += 256) (&t2[0][0][0])[i] = 0.f;
    }

    // conv1 weights: uniform indices -> scalar regs
    float wa[64];
#pragma unroll
    for (int i = 0; i < 64; ++i) wa[i] = w1[i];
    __syncthreads();

    // ---------------- stage 1: conv1(2->8,k2,s2) + floor(relu) + maxpool2 -> t1
    // Row-pair processing keeps the input patch at 16 VGPRs instead of 32.
    {
        const float* xb = x + (size_t)n * (2 * 128 * 128);
#pragma unroll 1
        for (int k = 0; k < 4; ++k) {
            int i = (k << 8) + t;          // pooled pixel 0..1023
            int py = i >> 5, px = i & 31;  // consecutive t -> consecutive px: coalesced float4

            float res[8];
#pragma unroll
            for (int co = 0; co < 8; ++co) res[co] = 0.f;   // floor(relu)>=0

#pragma unroll
            for (int half = 0; half < 2; ++half) {          // conv output row pair (oy)
                float p[2][2][4];                           // [c][kh][x]
#pragma unroll
                for (int c = 0; c < 2; ++c)
#pragma unroll
                    for (int r = 0; r < 2; ++r) {
                        float4 v = *reinterpret_cast<const float4*>(
                            xb + (c * 128 + 4 * py + 2 * half + r) * 128 + 4 * px);
                        p[c][r][0] = v.x; p[c][r][1] = v.y; p[c][r][2] = v.z; p[c][r][3] = v.w;
                    }
#pragma unroll
                for (int ox = 0; ox < 2; ++ox)
#pragma unroll
                for (int co = 0; co < 8; ++co) {
                    float a = 0.f;
#pragma unroll
                    for (int c = 0; c < 2; ++c)
#pragma unroll
                    for (int kh = 0; kh < 2; ++kh)
#pragma unroll
                    for (int kw = 0; kw < 2; ++kw)
                        a += p[c][kh][2 * ox + kw] * wa[((co * 2 + c) * 2 + kh) * 2 + kw];
                    res[co] = fmaxf(res[co], floorf(fmaxf(a, 0.f)));
                }
            }
#pragma unroll
            for (int co = 0; co < 8; ++co)
                t1[co][py + 1][px + 1] = f2bf(res[co]);
        }
    }
    __syncthreads();

    // ---------------- stage 2: conv2(3x3,p1) + floor(relu) + maxpool2 -> t2
    {
        const int py = t >> 4, px = t & 15;   // pooled pixel; all 8 co per thread
        float acc[8][2][2];
#pragma unroll
        for (int i = 0; i < 32; ++i) (&acc[0][0][0])[i] = 0.f;

#pragma unroll 1
        for (int ci = 0; ci < 8; ++ci) {
            float p[4][4];                    // 4x4 patch reused by 8 co
#pragma unroll
            for (int r = 0; r < 4; ++r) {
                // row base is uint-aligned (even element index); 2 packed-bf16 reads
                const unsigned int* rp = (const unsigned int*)&t1[ci][2 * py + r][0];
                unsigned int u0 = rp[px];       // elements 2px, 2px+1
                unsigned int u1 = rp[px + 1];   // elements 2px+2, 2px+3
                p[r][0] = bf_lo(u0); p[r][1] = bf_hi(u0);
                p[r][2] = bf_lo(u1); p[r][3] = bf_hi(u1);
            }
#pragma unroll
            for (int co = 0; co < 8; ++co) {
                const float* wp = w2 + (co * 8 + ci) * 9;   // uniform -> s_load
                float wv[9];
#pragma unroll
                for (int i = 0; i < 9; ++i) wv[i] = wp[i];
#pragma unroll
                for (int oy = 0; oy < 2; ++oy)
#pragma unroll
                for (int ox = 0; ox < 2; ++ox) {
                    float a = acc[co][oy][ox];
#pragma unroll
                    for (int kh = 0; kh < 3; ++kh)
#pragma unroll
                    for (int kw = 0; kw < 3; ++kw)
                        a += p[oy + kh][ox + kw] * wv[kh * 3 + kw];
                    acc[co][oy][ox] = a;
                }
            }
        }
#pragma unroll
        for (int co = 0; co < 8; ++co) {
            float m = 0.f;
#pragma unroll
            for (int oy = 0; oy < 2; ++oy)
#pragma unroll
            for (int ox = 0; ox < 2; ++ox)
                m = fmaxf(m, floorf(fmaxf(acc[co][oy][ox], 0.f)));
            t2[co][py + 1][px + 1] = m;
        }
    }
    __syncthreads();

    // ------- stage 3: conv3(3x3,p1) + floor(relu) + maxpool2 + FC(512->2) -------
    {
        const int co2 = __builtin_amdgcn_readfirstlane(t >> 6);  // wave-uniform
        const int l = t & 63;
        const int py = l >> 3, px = l & 7;

        float acc[2][2][2];
#pragma unroll
        for (int i = 0; i < 8; ++i) (&acc[0][0][0])[i] = 0.f;

#pragma unroll 1
        for (int ci = 0; ci < 8; ++ci) {
            float p[4][4];
#pragma unroll
            for (int r = 0; r < 4; ++r) {
                const float2* row = reinterpret_cast<const float2*>(&t2[ci][2 * py + r][0]);
                float2 a = row[px], b = row[px + 1];
                p[r][0] = a.x; p[r][1] = a.y; p[r][2] = b.x; p[r][3] = b.y;
            }
#pragma unroll
            for (int cc = 0; cc < 2; ++cc) {
                const float* wp = w3 + ((2 * co2 + cc) * 8 + ci) * 9;  // scalar
                float wv[9];
#pragma unroll
                for (int i = 0; i < 9; ++i) wv[i] = wp[i];
#pragma unroll
                for (int oy = 0; oy < 2; ++oy)
#pragma unroll
                for (int ox = 0; ox < 2; ++ox) {
                    float a = acc[cc][oy][ox];
#pragma unroll
                    for (int kh = 0; kh < 3; ++kh)
#pragma unroll
                    for (int kw = 0; kw < 3; ++kw)
                        a += p[oy + kh][ox + kw] * wv[kh * 3 + kw];
                    acc[cc][oy][ox] = a;
                }
            }
        }

        float p0 = 0.f, p1 = 0.f;
#pragma unroll
        for (int cc = 0; cc < 2; ++cc) {
            float m = 0.f;
#pragma unroll
            for (int oy = 0; oy < 2; ++oy)
#pragma unroll
            for (int ox = 0; ox < 2; ++ox)
                m = fmaxf(m, floorf(fmaxf(acc[cc][oy][ox], 0.f)));
            int o = (2 * co2 + cc) * 64 + l;
            p0 += m * wfc[o];
            p1 += m * wfc[512 + o];
        }

#pragma unroll
        for (int off = 32; off > 0; off >>= 1) {
            p0 += __shfl_down(p0, off);
            p1 += __shfl_down(p1, off);
        }
        if (l == 0) { red[co2 * 2 + 0] = p0; red[co2 * 2 + 1] = p1; }
    }
    __syncthreads();

    if (t == 0) {
        out[n * 2 + 0] = red[0] + red[2] + red[4] + red[6];
        out[n * 2 + 1] = red[1] + red[3] + red[5] + red[7];
    }
}

extern "C" void kernel_launch(void* const* d_in, const int* in_sizes, int n_in,
                              void* d_out, int out_size, void* d_ws, size_t ws_size,
                              hipStream_t stream) {
    const float* x   = (const float*)d_in[0];
    const float* w1  = (const float*)d_in[1];
    const float* w2  = (const float*)d_in[2];
    const float* w3  = (const float*)d_in[3];
    const float* wfc = (const float*)d_in[4];
    float* outp = (float*)d_out;

    fused_snn<<<1024, 256, 0, stream>>>(x, w1, w2, w3, wfc, outp);
}

// Round 4
// 205.719 us; speedup vs baseline: 1.0434x; 1.0434x over previous
//
#include <hip/hip_runtime.h>
#include <cstddef>

// SNN collapse: alpha = expf(-1/0.005) = expf(-200) == 0.0f in fp32, so
// LIF(spiking) == floor(relu(x)) elementwise and LIF(readout) == identity.
// (Verified R1-R3: absmax 0.0.) Per-image feed-forward CNN, fully fused,
// one block per image, intermediates in LDS (t1 in bf16: values are small
// non-negative integers, exact in bf16).
//
// R4: packed fp32 math (v_pk_fma_f32) — accumulate channel PAIRS as
// <2 x float> with splatted activations; halves conv VALU instruction count.
// launch_bounds(256,4): grid is 1024 blocks = 4/CU, >4 occupancy is useless.

typedef __attribute__((ext_vector_type(2))) float f2;

__device__ __forceinline__ f2 splat(float v) { f2 r; r.x = v; r.y = v; return r; }
__device__ __forceinline__ float bf_lo(unsigned int u) {
    union { unsigned int i; float f; } c; c.i = u << 16; return c.f;
}
__device__ __forceinline__ float bf_hi(unsigned int u) {
    union { unsigned int i; float f; } c; c.i = u & 0xffff0000u; return c.f;
}
__device__ __forceinline__ unsigned short f2bf(float f) {
    union { float f; unsigned int i; } c; c.f = f; return (unsigned short)(c.i >> 16);
}
__device__ __forceinline__ float spk(float a) {   // floor(relu(x))
    return floorf(fmaxf(a, 0.f));
}

__global__ __launch_bounds__(256, 4) void fused_snn(
    const float* __restrict__ x,    // (1024,2,128,128)
    const float* __restrict__ w1,   // (8,2,2,2)
    const float* __restrict__ w2,   // (8,8,3,3)
    const float* __restrict__ w3,   // (8,8,3,3)
    const float* __restrict__ wfc,  // (2,512)
    float* __restrict__ out)        // (1024,2)
{
    __shared__ unsigned short t1[8][34][34];        // conv1 pooled out, bf16, zero-padded: 18.5 KB
    __shared__ __align__(16) float t2[8][18][18];   // conv2 pooled out, fp32, zero-padded: 10.4 KB
    __shared__ float red[8];

    const int n = blockIdx.x;
    const int t = threadIdx.x;

    // zero-init LDS (borders must be zero)
    {
        unsigned int* z1 = (unsigned int*)&t1[0][0][0];   // 9248 ushorts = 4624 uints
        for (int i = t; i < 4624; i += 256) z1[i] = 0u;
        for (int i = t; i < 8 * 18 * 18; i += 256) (&t2[0][0][0])[i] = 0.f;
    }

    // conv1 weights as co-pairs: wp1[co2][j] = (w1[2co2][j], w1[2co2+1][j]), j = c*4+kh*2+kw
    f2 wp1[4][8];
#pragma unroll
    for (int co2 = 0; co2 < 4; ++co2)
#pragma unroll
        for (int j = 0; j < 8; ++j) {
            wp1[co2][j].x = w1[(2 * co2) * 8 + j];       // uniform -> scalar loads
            wp1[co2][j].y = w1[(2 * co2 + 1) * 8 + j];
        }
    __syncthreads();

    // ---------------- stage 1: conv1(2->8,k2,s2) + floor(relu) + maxpool2 -> t1
    {
        const float* xb = x + (size_t)n * (2 * 128 * 128);
#pragma unroll 2
        for (int k = 0; k < 4; ++k) {
            int i = (k << 8) + t;          // pooled pixel 0..1023
            int py = i >> 5, px = i & 31;  // consecutive t -> consecutive px: coalesced float4

            f2 r2[4];
#pragma unroll
            for (int co2 = 0; co2 < 4; ++co2) r2[co2] = splat(0.f);  // floor(relu)>=0

#pragma unroll
            for (int half = 0; half < 2; ++half) {          // pooled-window row pair (oy)
                float p[2][2][4];                           // [c][kh][x]
#pragma unroll
                for (int c = 0; c < 2; ++c)
#pragma unroll
                    for (int r = 0; r < 2; ++r) {
                        float4 v = *reinterpret_cast<const float4*>(
                            xb + (c * 128 + 4 * py + 2 * half + r) * 128 + 4 * px);
                        p[c][r][0] = v.x; p[c][r][1] = v.y; p[c][r][2] = v.z; p[c][r][3] = v.w;
                    }
#pragma unroll
                for (int ox = 0; ox < 2; ++ox)
#pragma unroll
                for (int co2 = 0; co2 < 4; ++co2) {
                    f2 a = splat(0.f);
#pragma unroll
                    for (int c = 0; c < 2; ++c)
#pragma unroll
                    for (int kh = 0; kh < 2; ++kh)
#pragma unroll
                    for (int kw = 0; kw < 2; ++kw)
                        a += splat(p[c][kh][2 * ox + kw]) * wp1[co2][c * 4 + kh * 2 + kw];
                    r2[co2].x = fmaxf(r2[co2].x, spk(a.x));
                    r2[co2].y = fmaxf(r2[co2].y, spk(a.y));
                }
            }
#pragma unroll
            for (int co2 = 0; co2 < 4; ++co2) {
                t1[2 * co2 + 0][py + 1][px + 1] = f2bf(r2[co2].x);
                t1[2 * co2 + 1][py + 1][px + 1] = f2bf(r2[co2].y);
            }
        }
    }
    __syncthreads();

    // ---------------- stage 2: conv2(3x3,p1) + floor(relu) + maxpool2 -> t2
    {
        const int py = t >> 4, px = t & 15;   // pooled pixel; all 8 co per thread
        f2 acc[4][2][2];                      // co-pairs
#pragma unroll
        for (int i = 0; i < 16; ++i) (&acc[0][0][0])[i] = splat(0.f);

#pragma unroll 1
        for (int ci = 0; ci < 8; ++ci) {
            float p[4][4];                    // 4x4 patch reused by 8 co
#pragma unroll
            for (int r = 0; r < 4; ++r) {
                const unsigned int* rp = (const unsigned int*)&t1[ci][2 * py + r][0];
                unsigned int u0 = rp[px];       // elements 2px, 2px+1 (row base uint-aligned)
                unsigned int u1 = rp[px + 1];   // elements 2px+2, 2px+3
                p[r][0] = bf_lo(u0); p[r][1] = bf_hi(u0);
                p[r][2] = bf_lo(u1); p[r][3] = bf_hi(u1);
            }
#pragma unroll
            for (int co2 = 0; co2 < 4; ++co2) {
                f2 wv[9];                      // uniform addresses -> scalar loads
#pragma unroll
                for (int j = 0; j < 9; ++j) {
                    wv[j].x = w2[((2 * co2 + 0) * 8 + ci) * 9 + j];
                    wv[j].y = w2[((2 * co2 + 1) * 8 + ci) * 9 + j];
                }
#pragma unroll
                for (int oy = 0; oy < 2; ++oy)
#pragma unroll
                for (int ox = 0; ox < 2; ++ox) {
                    f2 a = acc[co2][oy][ox];
#pragma unroll
                    for (int kh = 0; kh < 3; ++kh)
#pragma unroll
                    for (int kw = 0; kw < 3; ++kw)
                        a += splat(p[oy + kh][ox + kw]) * wv[kh * 3 + kw];
                    acc[co2][oy][ox] = a;
                }
            }
        }
#pragma unroll
        for (int co2 = 0; co2 < 4; ++co2) {
            float mx = 0.f, my = 0.f;
#pragma unroll
            for (int oy = 0; oy < 2; ++oy)
#pragma unroll
            for (int ox = 0; ox < 2; ++ox) {
                mx = fmaxf(mx, spk(acc[co2][oy][ox].x));
                my = fmaxf(my, spk(acc[co2][oy][ox].y));
            }
            t2[2 * co2 + 0][py + 1][px + 1] = mx;
            t2[2 * co2 + 1][py + 1][px + 1] = my;
        }
    }
    __syncthreads();

    // ------- stage 3: conv3(3x3,p1) + floor(relu) + maxpool2 + FC(512->2) -------
    {
        const int co2 = __builtin_amdgcn_readfirstlane(t >> 6);  // wave-uniform: co pair {2co2, 2co2+1}
        const int l = t & 63;
        const int py = l >> 3, px = l & 7;

        f2 acc[2][2];                         // cc in vector lanes
#pragma unroll
        for (int i = 0; i < 4; ++i) (&acc[0][0])[i] = splat(0.f);

#pragma unroll 1
        for (int ci = 0; ci < 8; ++ci) {
            float p[4][4];
#pragma unroll
            for (int r = 0; r < 4; ++r) {
                const float2* row = reinterpret_cast<const float2*>(&t2[ci][2 * py + r][0]);
                float2 a = row[px], b = row[px + 1];
                p[r][0] = a.x; p[r][1] = a.y; p[r][2] = b.x; p[r][3] = b.y;
            }
            f2 wv[9];                          // co2 wave-uniform -> scalar loads
#pragma unroll
            for (int j = 0; j < 9; ++j) {
                wv[j].x = w3[((2 * co2 + 0) * 8 + ci) * 9 + j];
                wv[j].y = w3[((2 * co2 + 1) * 8 + ci) * 9 + j];
            }
#pragma unroll
            for (int oy = 0; oy < 2; ++oy)
#pragma unroll
            for (int ox = 0; ox < 2; ++ox) {
                f2 a = acc[oy][ox];
#pragma unroll
                for (int kh = 0; kh < 3; ++kh)
#pragma unroll
                for (int kw = 0; kw < 3; ++kw)
                    a += splat(p[oy + kh][ox + kw]) * wv[kh * 3 + kw];
                acc[oy][ox] = a;
            }
        }

        // pool + floor + FC partials; flattened feature o = co*64 + l
        float mx = 0.f, my = 0.f;
#pragma unroll
        for (int oy = 0; oy < 2; ++oy)
#pragma unroll
        for (int ox = 0; ox < 2; ++ox) {
            mx = fmaxf(mx, spk(acc[oy][ox].x));
            my = fmaxf(my, spk(acc[oy][ox].y));
        }
        int o0 = (2 * co2 + 0) * 64 + l;
        int o1 = (2 * co2 + 1) * 64 + l;
        float p0 = mx * wfc[o0] + my * wfc[o1];          // lanes consecutive -> coalesced
        float p1 = mx * wfc[512 + o0] + my * wfc[512 + o1];

#pragma unroll
        for (int off = 32; off > 0; off >>= 1) {
            p0 += __shfl_down(p0, off);
            p1 += __shfl_down(p1, off);
        }
        if (l == 0) { red[co2 * 2 + 0] = p0; red[co2 * 2 + 1] = p1; }
    }
    __syncthreads();

    if (t == 0) {
        out[n * 2 + 0] = red[0] + red[2] + red[4] + red[6];
        out[n * 2 + 1] = red[1] + red[3] + red[5] + red[7];
    }
}

extern "C" void kernel_launch(void* const* d_in, const int* in_sizes, int n_in,
                              void* d_out, int out_size, void* d_ws, size_t ws_size,
                              hipStream_t stream) {
    const float* x   = (const float*)d_in[0];
    const float* w1  = (const float*)d_in[1];
    const float* w2  = (const float*)d_in[2];
    const float* w3  = (const float*)d_in[3];
    const float* wfc = (const float*)d_in[4];
    float* outp = (float*)d_out;

    fused_snn<<<1024, 256, 0, stream>>>(x, w1, w2, w3, wfc, outp);
}